// Round 5
// baseline (347.906 us; speedup 1.0000x reference)
//
#include <hip/hip_runtime.h>
#include <cstdint>

typedef _Float16 f16;
typedef f16 f16x8 __attribute__((ext_vector_type(8)));
typedef f16 f16x4 __attribute__((ext_vector_type(4)));
typedef f16 f16x2 __attribute__((ext_vector_type(2)));
typedef float f32x4 __attribute__((ext_vector_type(4)));

#define D_MODEL 1280
#define SEQ 2048
#define BATCH 4
#define HEADS 8
#define HDIM 160
#define MTOT (BATCH*SEQ)          // 8192
#define NQKV (3*D_MODEL)          // 3840

__device__ __forceinline__ void gload_lds16(const f16* g, f16* l) {
  __builtin_amdgcn_global_load_lds(
      (const __attribute__((address_space(1))) unsigned int*)g,
      (__attribute__((address_space(3))) unsigned int*)l,
      16, 0, 0);
}

#define BARX() { asm volatile("" ::: "memory"); __builtin_amdgcn_s_barrier(); asm volatile("" ::: "memory"); }
#define VMW(N) { asm volatile("s_waitcnt vmcnt(" #N ")" ::: "memory"); }

// ---------------- prep kernels ----------------

__global__ void convert_f32_to_f16(const float* __restrict__ in, f16* __restrict__ out, int n4) {
  int i = blockIdx.x * 256 + threadIdx.x;
  if (i < n4) {
    float4 v = ((const float4*)in)[i];
    f16x4 o = { (f16)v.x, (f16)v.y, (f16)v.z, (f16)v.w };
    ((f16x4*)out)[i] = o;
  }
}

// W_eff[o][i] = W[o][i] + sum_r up[o][r]*down[r][i]   (all 1280x1280, rank 4)
__global__ void build_weff(const float* __restrict__ W, const float* __restrict__ up,
                           const float* __restrict__ down, f16* __restrict__ out) {
  int idx = blockIdx.x * 256 + threadIdx.x;          // D*D/4 threads
  int o  = idx / (D_MODEL / 4);
  int i0 = (idx % (D_MODEL / 4)) * 4;
  float4 w = *(const float4*)&W[(size_t)o * D_MODEL + i0];
  float u0 = up[o*4+0], u1 = up[o*4+1], u2 = up[o*4+2], u3 = up[o*4+3];
  float vals[4] = { w.x, w.y, w.z, w.w };
  f16x4 r;
#pragma unroll
  for (int j = 0; j < 4; ++j) {
    int i = i0 + j;
    float acc = vals[j] + u0*down[i] + u1*down[D_MODEL + i]
                        + u2*down[2*D_MODEL + i] + u3*down[3*D_MODEL + i];
    r[j] = (f16)acc;
  }
  *(f16x4*)&out[(size_t)o * D_MODEL + i0] = r;
}

// V slice of qkv [8192][3840] (cols 2560..3839) -> Vt [32 bh][160 d][2048 s]
__global__ void transpose_v(const f16* __restrict__ qkv, f16* __restrict__ Vt) {
  __shared__ f16 t[32][33];
  int s0 = blockIdx.x * 32;
  int d0 = blockIdx.y * 32;
  int bh = blockIdx.z;
  int b = bh >> 3, h = bh & 7;
  int j = threadIdx.x & 31;
  int i0 = threadIdx.x >> 5;
#pragma unroll
  for (int k = 0; k < 4; ++k) {
    int i = i0 + k * 8;
    t[i][j] = qkv[(size_t)(b*SEQ + s0 + i) * NQKV + 2*D_MODEL + h*HDIM + d0 + j];
  }
  __syncthreads();
#pragma unroll
  for (int k = 0; k < 4; ++k) {
    int i = i0 + k * 8;
    Vt[(size_t)(bh*HDIM + d0 + i) * SEQ + s0 + j] = t[j][i];
  }
}

// ---------------- 256x256 deep-pipelined GEMM: C[M][N](f16) = A[M][K] * Bw[N][K]^T ----
__global__ __launch_bounds__(512) void gemm256(const f16* __restrict__ A,
                                               const f16* __restrict__ Bw,
                                               f16* __restrict__ C) {
  const int K = D_MODEL, ldc = NQKV, NT = D_MODEL/64;   // 20 K-tiles
  __shared__ alignas(16) f16 lds[7 * 8192];             // A: slots 0..2, B: slots 3..6
  f16* LB = lds + 3*8192;
  int tid = threadIdx.x;
  int wv = tid >> 6, l = tid & 63;
  int wm = wv >> 2, wn = wv & 3;
  int lr = l & 15, lg = l >> 4;
  int bm = blockIdx.y, bn = blockIdx.x;

  int row0 = tid >> 3;
  int csw  = ((tid & 7) ^ (row0 & 7)) * 8;
  const f16* Asrc[2]; const f16* Bsrc[2];
#pragma unroll
  for (int h = 0; h < 2; ++h) {
    Asrc[h] = A  + (size_t)(bm*256 + h*128 + row0) * K + csw;
    Bsrc[h] = Bw + (size_t)(bn*256 + h*128 + row0) * K + csw;
  }
  int ldsoff = wv * 512;

  int xsl0 = ((lg)     ^ (lr & 7)) * 8;
  int xsl1 = ((4 + lg) ^ (lr & 7)) * 8;

  f32x4 acc[8][4] = {};

#define STAGE_A(h, slot, kt) { const f16* s_ = Asrc[h] + (kt)*64; f16* d_ = lds + (slot)*8192 + ldsoff; \
    gload_lds16(s_, d_); gload_lds16(s_ + (size_t)64*K, d_ + 4096); }
#define STAGE_B(h, slot, kt) { const f16* s_ = Bsrc[h] + (kt)*64; f16* d_ = LB + (slot)*8192 + ldsoff; \
    gload_lds16(s_, d_); gload_lds16(s_ + (size_t)64*K, d_ + 4096); }

  STAGE_A(0, 0, 0); STAGE_A(1, 1, 0);
  STAGE_B(0, 0, 0); STAGE_B(1, 1, 0);
  STAGE_B(0, 2, 1);
  VMW(2); BARX();

  for (int t = 0; t < NT; ++t) {
    int sA0 = (2*t) % 3, sA1 = (2*t+1) % 3, sA2 = (2*t+2) % 3;
    int sB0 = (2*t) & 3, sB1 = (2*t+1) & 3, sB3 = (2*t+3) & 3;
    int tc1 = (t+1 < NT) ? t+1 : NT-1;
    int tc2 = (t+2 < NT) ? t+2 : NT-1;

#define PHASE(ah, bh, sA, sB, STG, VMOPT) { \
    f16x8 af[4][2], bf[2][2]; \
    _Pragma("unroll") \
    for (int j = 0; j < 4; ++j) { \
      int base = (sA)*8192 + (wm*64 + j*16 + lr)*64; \
      af[j][0] = *(const f16x8*)&lds[base + xsl0]; \
      af[j][1] = *(const f16x8*)&lds[base + xsl1]; \
    } \
    _Pragma("unroll") \
    for (int i = 0; i < 2; ++i) { \
      int base = (sB)*8192 + (wn*32 + i*16 + lr)*64; \
      bf[i][0] = *(const f16x8*)&LB[base + xsl0]; \
      bf[i][1] = *(const f16x8*)&LB[base + xsl1]; \
    } \
    STG; \
    BARX(); \
    __builtin_amdgcn_s_setprio(1); \
    _Pragma("unroll") \
    for (int j = 0; j < 4; ++j) \
      _Pragma("unroll") \
      for (int i = 0; i < 2; ++i) { \
        acc[(ah)*4+j][(bh)*2+i] = __builtin_amdgcn_mfma_f32_16x16x32_f16(af[j][0], bf[i][0], acc[(ah)*4+j][(bh)*2+i], 0, 0, 0); \
        acc[(ah)*4+j][(bh)*2+i] = __builtin_amdgcn_mfma_f32_16x16x32_f16(af[j][1], bf[i][1], acc[(ah)*4+j][(bh)*2+i], 0, 0, 0); \
      } \
    __builtin_amdgcn_s_setprio(0); \
    VMOPT; \
    BARX(); }

    PHASE(0, 0, sA0, sB0, STAGE_B(1, sB3, tc1), VMW(2))
    PHASE(1, 0, sA1, sB0, STAGE_A(0, sA2, tc1), )
    PHASE(0, 1, sA0, sB1, STAGE_B(0, sB0, tc2), )
    PHASE(1, 1, sA1, sB1, STAGE_A(1, sA0, tc1), VMW(4))
#undef PHASE
  }

#pragma unroll
  for (int mf = 0; mf < 8; ++mf) {
    int r0 = bm*256 + (mf>>2)*128 + wm*64 + (mf&3)*16 + lg*4;
#pragma unroll
    for (int nf = 0; nf < 4; ++nf) {
      int c = bn*256 + (nf>>1)*128 + wn*32 + (nf&1)*16 + lr;
#pragma unroll
      for (int rg = 0; rg < 4; ++rg)
        C[(size_t)(r0 + rg) * ldc + c] = (f16)acc[mf][nf][rg];
    }
  }
#undef STAGE_A
#undef STAGE_B
}

// ---------------- GEMM: C[M][N] = A[M][K] * Bw[N][K]^T  (+bias, f32 out) ----------------

template<int OUTF16>
__global__ __launch_bounds__(256) void gemm_bt(
    const f16* __restrict__ A, int lda,
    const f16* __restrict__ Bw,                 // [N][K], ldb = K
    void* __restrict__ Cp, int ldc,
    const float* __restrict__ bias,
    int N, int K) {
  __shared__ alignas(16) f16 As[128 * 32];
  __shared__ alignas(16) f16 Bs[128 * 32];
  int tid = threadIdx.x;
  int w = tid >> 6, l = tid & 63;
  int wm = w >> 1, wn = w & 1;
  int bm = blockIdx.y, bn = blockIdx.x;
  int lr = l & 15, lg = l >> 4;

  f32x4 acc[4][4] = {};

  const int srow = w * 32 + (l >> 2);
  const int scol = (l & 3) * 8;
  const f16* Ab = A  + (size_t)(bm*128 + srow) * lda + scol;
  const f16* Bb = Bw + (size_t)(bn*128 + srow) * K   + scol;
  f16* AsW = &As[w * 1024];
  f16* BsW = &Bs[w * 1024];

  for (int k0 = 0; k0 < K; k0 += 32) {
    gload_lds16(Ab + k0,                     AsW);
    gload_lds16(Ab + k0 + (size_t)16 * lda,  AsW + 512);
    gload_lds16(Bb + k0,                     BsW);
    gload_lds16(Bb + k0 + (size_t)16 * K,    BsW + 512);
    __syncthreads();
    f16x8 af[4], bf[4];
#pragma unroll
    for (int f = 0; f < 4; ++f) {
      af[f] = *(const f16x8*)&As[(wm*64 + f*16 + lr) * 32 + lg * 8];
      bf[f] = *(const f16x8*)&Bs[(wn*64 + f*16 + lr) * 32 + lg * 8];
    }
    __builtin_amdgcn_s_setprio(1);
#pragma unroll
    for (int fr = 0; fr < 4; ++fr)
#pragma unroll
      for (int fc = 0; fc < 4; ++fc)
        acc[fr][fc] = __builtin_amdgcn_mfma_f32_16x16x32_f16(af[fr], bf[fc], acc[fr][fc], 0, 0, 0);
    __builtin_amdgcn_s_setprio(0);
    __syncthreads();
  }

#pragma unroll
  for (int fr = 0; fr < 4; ++fr) {
    int r0 = bm*128 + wm*64 + fr*16 + lg*4;
#pragma unroll
    for (int fc = 0; fc < 4; ++fc) {
      int c = bn*128 + wn*64 + fc*16 + lr;
#pragma unroll
      for (int rg = 0; rg < 4; ++rg) {
        size_t off = (size_t)(r0 + rg) * ldc + c;
        if (OUTF16) ((f16*)Cp)[off] = (f16)acc[fr][fc][rg];
        else        ((float*)Cp)[off] = acc[fr][fc][rg] + bias[c];
      }
    }
  }
}

// ---------------- flash attention (counted-vmcnt pipeline) ----------------
// grid: (32 q-tiles, 32 bh); 256 thr (4 waves); each wave owns 16 q rows.
// Swapped QK^T: S^T[kr][q] via mfma(K, Q); PV as O^T = V^T * P^T.
// Single-buffered K [64][168] and V [160][64] (XOR-swizzled), but loads are
// issued immediately after each buffer's last reader (post-barrier) and waited
// with COUNTED vmcnt one phase later — no vmcnt(0) drains in the loop.
// Per iter: QK^T | b0 | issue K[kt+1] | softmax | vmcnt(6) b1 | PV | b2 |
//           issue V[kt+1] | vmcnt(5) b3.
__global__ __launch_bounds__(256, 3) void attn(const f16* __restrict__ qkv,
                                               const f16* __restrict__ Vt,
                                               f16* __restrict__ ctx) {
  __shared__ alignas(16) f16 Kl[64 * 168];   // 21504 B
  __shared__ alignas(16) f16 Vl[160 * 64];   // 20480 B
  __shared__ alignas(16) f16 Pl[64 * 72];    //  9216 B
  int tid = threadIdx.x;
  int wv = tid >> 6, l = tid & 63;
  int lr = l & 15, lg = l >> 4;
  int qt = blockIdx.x, bh = blockIdx.y;
  int b = bh >> 3, h = bh & 7;
  const size_t qrow = (size_t)(b*SEQ + qt*64 + wv*16 + lr);

  const f16 qscale = (f16)0.114055069f;
  f16x8 qf[5];
#pragma unroll
  for (int dk = 0; dk < 5; ++dk) {
    f16x8 t = *(const f16x8*)&qkv[qrow * NQKV + h*HDIM + dk*32 + lg*8];
#pragma unroll
    for (int j = 0; j < 8; ++j) t[j] = t[j] * qscale;
    qf[dk] = t;
  }

  // K staging: 1344 chunks as 6 wave-uniform insts/wave.
  // it<5: chunks it*256 + wv*64 + lane;  it=5: chunks 1280+lane (all waves dup).
  const char* Kg0 = (const char*)qkv + (size_t)(b*SEQ)*NQKV*2 + (size_t)D_MODEL*2 + (size_t)h*HDIM*2;
  char* KlB = (char*)Kl;
  uint32_t koff[6];
  f16* kld[6];
#pragma unroll
  for (int it = 0; it < 6; ++it) {
    int p = (it < 5) ? it*256 + tid : 1280 + (tid & 63);
    koff[it] = (uint32_t)(p/21) * (NQKV*2) + (uint32_t)(p%21) * 16;
    kld[it] = (f16*)(KlB + ((it < 5) ? (it*256 + wv*64)*16 : 1280*16));
  }

  // V staging: 1280 chunks (5 insts/wave), content XOR-swizzled via global src.
  const char* Vg0 = (const char*)Vt + (size_t)bh*HDIM*SEQ*2;
  char* VlB = (char*)Vl;
  uint32_t voff[5];
  f16* vld[5];
#pragma unroll
  for (int it = 0; it < 5; ++it) {
    int c = it*256 + tid;
    int row = c >> 3, sp = c & 7;
    voff[it] = (uint32_t)row * (SEQ*2) + (uint32_t)((sp ^ (row & 7)) * 16);
    vld[it] = (f16*)(VlB + (it*256 + wv*64)*16);
  }
  uint32_t vro[2];
#pragma unroll
  for (int ks = 0; ks < 2; ++ks)
    vro[ks] = (uint32_t)lr*128 + (uint32_t)((((ks*4+lg) ^ (lr & 7)) * 16));

  f32x4 oacc[10] = {};
  float m = -1e30f, lsum = 0.f;

  // prologue: stage K[0] (6) then V[0] (5); wait K only (counted), V stays in flight
  {
    const char* Ksrc = Kg0;
    const char* Vsrc = Vg0;
#pragma unroll
    for (int it = 0; it < 6; ++it) gload_lds16((const f16*)(Ksrc + koff[it]), kld[it]);
#pragma unroll
    for (int it = 0; it < 5; ++it) gload_lds16((const f16*)(Vsrc + voff[it]), vld[it]);
  }
  VMW(5); BARX();

  for (int kt = 0; kt < 32; ++kt) {
    int ktn = (kt+1 < 32) ? kt+1 : 31;   // clamp: uniform counts, redundant same-data restage
    // ---- QK^T from Kl (K[kt] resident; V[kt] in flight: 5 outstanding)
    f32x4 sc[4] = {};
    __builtin_amdgcn_s_setprio(1);
#pragma unroll
    for (int kb = 0; kb < 4; ++kb)
#pragma unroll
      for (int dk = 0; dk < 5; ++dk) {
        f16x8 a = *(const f16x8*)&Kl[(kb*16 + lr)*168 + dk*32 + lg*8];
        sc[kb] = __builtin_amdgcn_mfma_f32_16x16x32_f16(a, qf[dk], sc[kb], 0, 0, 0);
      }
    __builtin_amdgcn_s_setprio(0);
    BARX();   // b0: all waves done reading Kl

    // ---- issue K[kt+1] into Kl (outstanding: 5V + 6K)
    {
      const char* Ksrc = Kg0 + (size_t)ktn * (64*NQKV*2);
#pragma unroll
      for (int it = 0; it < 6; ++it) gload_lds16((const f16*)(Ksrc + koff[it]), kld[it]);
    }

    // ---- softmax (exp2 domain), lane owns q-row lr
    float ps[16];
    float smax = -1e30f;
#pragma unroll
    for (int kb = 0; kb < 4; ++kb)
#pragma unroll
      for (int rg = 0; rg < 4; ++rg) {
        float s = sc[kb][rg];
        ps[kb*4 + rg] = s;
        smax = fmaxf(smax, s);
      }
    smax = fmaxf(smax, __shfl_xor(smax, 16));
    smax = fmaxf(smax, __shfl_xor(smax, 32));
    if (!__all(smax <= m + 11.54f)) {
      float mn = fmaxf(m, smax);
      float alpha = exp2f(m - mn);
#pragma unroll
      for (int df = 0; df < 10; ++df)
#pragma unroll
        for (int rg = 0; rg < 4; ++rg) oacc[df][rg] *= alpha;
      lsum *= alpha;
      m = mn;
    }
    float psum = 0.f;
#pragma unroll
    for (int i = 0; i < 16; ++i) { float p = exp2f(ps[i] - m); ps[i] = p; psum += p; }
    psum += __shfl_xor(psum, 16);
    psum += __shfl_xor(psum, 32);
    lsum += psum;

    VMW(6); BARX();   // b1: V[kt] landed everywhere (5 oldest retired; 6 K still in flight)

    // ---- P round-trip (wave-private rows; no cross-wave hazard)
#pragma unroll
    for (int kb = 0; kb < 4; ++kb) {
      f16x4 pv = { (f16)ps[kb*4+0], (f16)ps[kb*4+1], (f16)ps[kb*4+2], (f16)ps[kb*4+3] };
      *(f16x4*)&Pl[(wv*16 + lr)*72 + kb*16 + lg*4] = pv;
    }
    f16x8 pb[2];
#pragma unroll
    for (int ks = 0; ks < 2; ++ks)
      pb[ks] = *(const f16x8*)&Pl[(wv*16 + lr)*72 + ks*32 + lg*8];

    // ---- PV from Vl
    __builtin_amdgcn_s_setprio(1);
#pragma unroll
    for (int df = 0; df < 10; ++df)
#pragma unroll
      for (int ks = 0; ks < 2; ++ks) {
        f16x8 a = *(const f16x8*)(VlB + vro[ks] + df*2048);
        oacc[df] = __builtin_amdgcn_mfma_f32_16x16x32_f16(a, pb[ks], oacc[df], 0, 0, 0);
      }
    __builtin_amdgcn_s_setprio(0);
    BARX();   // b2: all waves done reading Vl

    // ---- issue V[kt+1] into Vl (outstanding: 6K + 5V)
    {
      const char* Vsrc = Vg0 + (size_t)ktn * 128;
#pragma unroll
      for (int it = 0; it < 5; ++it) gload_lds16((const f16*)(Vsrc + voff[it]), vld[it]);
    }
    VMW(5); BARX();   // b3: K[kt+1] landed everywhere (6 retired; 5 V in flight)
  }

  float inv = 1.f / lsum;
#pragma unroll
  for (int df = 0; df < 10; ++df)
#pragma unroll
    for (int pr = 0; pr < 2; ++pr) {
      f16x2 pv = { (f16)(oacc[df][pr*2+0] * inv), (f16)(oacc[df][pr*2+1] * inv) };
      *(f16x2*)&ctx[qrow * D_MODEL + h*HDIM + df*16 + lg*4 + pr*2] = pv;
    }
}

// ---------------- launcher ----------------

extern "C" void kernel_launch(void* const* d_in, const int* in_sizes, int n_in,
                              void* d_out, int out_size, void* d_ws, size_t ws_size,
                              hipStream_t stream) {
  const float* x   = (const float*)d_in[0];
  const float* Wq  = (const float*)d_in[1];
  const float* Wk  = (const float*)d_in[2];
  const float* Wv  = (const float*)d_in[3];
  const float* Wo  = (const float*)d_in[4];
  const float* bo  = (const float*)d_in[5];
  const float* q_down = (const float*)d_in[6];
  const float* q_up   = (const float*)d_in[7];
  const float* k_down = (const float*)d_in[8];
  const float* k_up   = (const float*)d_in[9];
  const float* v_down = (const float*)d_in[10];
  const float* v_up   = (const float*)d_in[11];
  const float* o_down = (const float*)d_in[12];
  const float* o_up   = (const float*)d_in[13];
  float* out = (float*)d_out;

  char* ws = (char*)d_ws;
  f16* xh    = (f16*)ws;                                  // 8192x1280 (reused as ctx)
  f16* Wqkv  = (f16*)(ws + 20971520);                     // 3840x1280
  f16* WoE   = (f16*)(ws + 20971520 + 9830400);           // 1280x1280
  f16* qkv   = (f16*)(ws + 20971520 + 9830400 + 3276800); // 8192x3840
  f16* Vt    = (f16*)(ws + 20971520 + 9830400 + 3276800 + 62914560); // 32x160x2048
  f16* ctx   = xh;

  convert_f32_to_f16<<<(MTOT*D_MODEL/4 + 255)/256, 256, 0, stream>>>(x, xh, MTOT*D_MODEL/4);
  build_weff<<<D_MODEL*D_MODEL/4/256, 256, 0, stream>>>(Wq, q_up, q_down, Wqkv);
  build_weff<<<D_MODEL*D_MODEL/4/256, 256, 0, stream>>>(Wk, k_up, k_down, Wqkv + (size_t)D_MODEL*D_MODEL);
  build_weff<<<D_MODEL*D_MODEL/4/256, 256, 0, stream>>>(Wv, v_up, v_down, Wqkv + (size_t)2*D_MODEL*D_MODEL);
  build_weff<<<D_MODEL*D_MODEL/4/256, 256, 0, stream>>>(Wo, o_up, o_down, WoE);

  gemm256<<<dim3(NQKV/256, MTOT/256), 512, 0, stream>>>(xh, Wqkv, qkv);
  transpose_v<<<dim3(SEQ/32, HDIM/32, BATCH*HEADS), 256, 0, stream>>>(qkv, Vt);
  attn<<<dim3(SEQ/64, BATCH*HEADS), 256, 0, stream>>>(qkv, Vt, ctx);
  gemm_bt<0><<<dim3(D_MODEL/128, MTOT/128), 256, 0, stream>>>(ctx, D_MODEL, WoE, out, D_MODEL,
                                                              bo, D_MODEL, D_MODEL);
  (void)in_sizes; (void)n_in; (void)out_size; (void)ws_size;
}

// Round 6
// 296.811 us; speedup vs baseline: 1.1721x; 1.1721x over previous
//
#include <hip/hip_runtime.h>
#include <cstdint>

typedef _Float16 f16;
typedef f16 f16x8 __attribute__((ext_vector_type(8)));
typedef f16 f16x4 __attribute__((ext_vector_type(4)));
typedef f16 f16x2 __attribute__((ext_vector_type(2)));
typedef float f32x4 __attribute__((ext_vector_type(4)));

#define D_MODEL 1280
#define SEQ 2048
#define BATCH 4
#define HEADS 8
#define HDIM 160
#define MTOT (BATCH*SEQ)          // 8192
#define NQKV (3*D_MODEL)          // 3840

__device__ __forceinline__ void gload_lds16(const f16* g, f16* l) {
  __builtin_amdgcn_global_load_lds(
      (const __attribute__((address_space(1))) unsigned int*)g,
      (__attribute__((address_space(3))) unsigned int*)l,
      16, 0, 0);
}

#define BARX() { asm volatile("" ::: "memory"); __builtin_amdgcn_s_barrier(); asm volatile("" ::: "memory"); }
#define VMW(N) { asm volatile("s_waitcnt vmcnt(" #N ")" ::: "memory"); }

// ---------------- prep kernels ----------------

__global__ void convert_f32_to_f16(const float* __restrict__ in, f16* __restrict__ out, int n4) {
  int i = blockIdx.x * 256 + threadIdx.x;
  if (i < n4) {
    float4 v = ((const float4*)in)[i];
    f16x4 o = { (f16)v.x, (f16)v.y, (f16)v.z, (f16)v.w };
    ((f16x4*)out)[i] = o;
  }
}

// W_eff[o][i] = W[o][i] + sum_r up[o][r]*down[r][i]   (all 1280x1280, rank 4)
__global__ void build_weff(const float* __restrict__ W, const float* __restrict__ up,
                           const float* __restrict__ down, f16* __restrict__ out) {
  int idx = blockIdx.x * 256 + threadIdx.x;          // D*D/4 threads
  int o  = idx / (D_MODEL / 4);
  int i0 = (idx % (D_MODEL / 4)) * 4;
  float4 w = *(const float4*)&W[(size_t)o * D_MODEL + i0];
  float u0 = up[o*4+0], u1 = up[o*4+1], u2 = up[o*4+2], u3 = up[o*4+3];
  float vals[4] = { w.x, w.y, w.z, w.w };
  f16x4 r;
#pragma unroll
  for (int j = 0; j < 4; ++j) {
    int i = i0 + j;
    float acc = vals[j] + u0*down[i] + u1*down[D_MODEL + i]
                        + u2*down[2*D_MODEL + i] + u3*down[3*D_MODEL + i];
    r[j] = (f16)acc;
  }
  *(f16x4*)&out[(size_t)o * D_MODEL + i0] = r;
}

// V slice of qkv [8192][3840] (cols 2560..3839) -> Vt [32 bh][160 d][2048 s]
__global__ void transpose_v(const f16* __restrict__ qkv, f16* __restrict__ Vt) {
  __shared__ f16 t[32][33];
  int s0 = blockIdx.x * 32;
  int d0 = blockIdx.y * 32;
  int bh = blockIdx.z;
  int b = bh >> 3, h = bh & 7;
  int j = threadIdx.x & 31;
  int i0 = threadIdx.x >> 5;
#pragma unroll
  for (int k = 0; k < 4; ++k) {
    int i = i0 + k * 8;
    t[i][j] = qkv[(size_t)(b*SEQ + s0 + i) * NQKV + 2*D_MODEL + h*HDIM + d0 + j];
  }
  __syncthreads();
#pragma unroll
  for (int k = 0; k < 4; ++k) {
    int i = i0 + k * 8;
    Vt[(size_t)(bh*HDIM + d0 + i) * SEQ + s0 + j] = t[j][i];
  }
}

// ---------------- 256x256 deep-pipelined GEMM: C[M][N](f16) = A[M][K] * Bw[N][K]^T ----
__global__ __launch_bounds__(512) void gemm256(const f16* __restrict__ A,
                                               const f16* __restrict__ Bw,
                                               f16* __restrict__ C) {
  const int K = D_MODEL, ldc = NQKV, NT = D_MODEL/64;   // 20 K-tiles
  __shared__ alignas(16) f16 lds[7 * 8192];             // A: slots 0..2, B: slots 3..6
  f16* LB = lds + 3*8192;
  int tid = threadIdx.x;
  int wv = tid >> 6, l = tid & 63;
  int wm = wv >> 2, wn = wv & 3;
  int lr = l & 15, lg = l >> 4;
  int bm = blockIdx.y, bn = blockIdx.x;

  int row0 = tid >> 3;
  int csw  = ((tid & 7) ^ (row0 & 7)) * 8;
  const f16* Asrc[2]; const f16* Bsrc[2];
#pragma unroll
  for (int h = 0; h < 2; ++h) {
    Asrc[h] = A  + (size_t)(bm*256 + h*128 + row0) * K + csw;
    Bsrc[h] = Bw + (size_t)(bn*256 + h*128 + row0) * K + csw;
  }
  int ldsoff = wv * 512;

  int xsl0 = ((lg)     ^ (lr & 7)) * 8;
  int xsl1 = ((4 + lg) ^ (lr & 7)) * 8;

  f32x4 acc[8][4] = {};

#define STAGE_A(h, slot, kt) { const f16* s_ = Asrc[h] + (kt)*64; f16* d_ = lds + (slot)*8192 + ldsoff; \
    gload_lds16(s_, d_); gload_lds16(s_ + (size_t)64*K, d_ + 4096); }
#define STAGE_B(h, slot, kt) { const f16* s_ = Bsrc[h] + (kt)*64; f16* d_ = LB + (slot)*8192 + ldsoff; \
    gload_lds16(s_, d_); gload_lds16(s_ + (size_t)64*K, d_ + 4096); }

  STAGE_A(0, 0, 0); STAGE_A(1, 1, 0);
  STAGE_B(0, 0, 0); STAGE_B(1, 1, 0);
  STAGE_B(0, 2, 1);
  VMW(2); BARX();

  for (int t = 0; t < NT; ++t) {
    int sA0 = (2*t) % 3, sA1 = (2*t+1) % 3, sA2 = (2*t+2) % 3;
    int sB0 = (2*t) & 3, sB1 = (2*t+1) & 3, sB3 = (2*t+3) & 3;
    int tc1 = (t+1 < NT) ? t+1 : NT-1;
    int tc2 = (t+2 < NT) ? t+2 : NT-1;

#define PHASE(ah, bh, sA, sB, STG, VMOPT) { \
    f16x8 af[4][2], bf[2][2]; \
    _Pragma("unroll") \
    for (int j = 0; j < 4; ++j) { \
      int base = (sA)*8192 + (wm*64 + j*16 + lr)*64; \
      af[j][0] = *(const f16x8*)&lds[base + xsl0]; \
      af[j][1] = *(const f16x8*)&lds[base + xsl1]; \
    } \
    _Pragma("unroll") \
    for (int i = 0; i < 2; ++i) { \
      int base = (sB)*8192 + (wn*32 + i*16 + lr)*64; \
      bf[i][0] = *(const f16x8*)&LB[base + xsl0]; \
      bf[i][1] = *(const f16x8*)&LB[base + xsl1]; \
    } \
    STG; \
    BARX(); \
    __builtin_amdgcn_s_setprio(1); \
    _Pragma("unroll") \
    for (int j = 0; j < 4; ++j) \
      _Pragma("unroll") \
      for (int i = 0; i < 2; ++i) { \
        acc[(ah)*4+j][(bh)*2+i] = __builtin_amdgcn_mfma_f32_16x16x32_f16(af[j][0], bf[i][0], acc[(ah)*4+j][(bh)*2+i], 0, 0, 0); \
        acc[(ah)*4+j][(bh)*2+i] = __builtin_amdgcn_mfma_f32_16x16x32_f16(af[j][1], bf[i][1], acc[(ah)*4+j][(bh)*2+i], 0, 0, 0); \
      } \
    __builtin_amdgcn_s_setprio(0); \
    VMOPT; \
    BARX(); }

    PHASE(0, 0, sA0, sB0, STAGE_B(1, sB3, tc1), VMW(2))
    PHASE(1, 0, sA1, sB0, STAGE_A(0, sA2, tc1), )
    PHASE(0, 1, sA0, sB1, STAGE_B(0, sB0, tc2), )
    PHASE(1, 1, sA1, sB1, STAGE_A(1, sA0, tc1), VMW(4))
#undef PHASE
  }

#pragma unroll
  for (int mf = 0; mf < 8; ++mf) {
    int r0 = bm*256 + (mf>>2)*128 + wm*64 + (mf&3)*16 + lg*4;
#pragma unroll
    for (int nf = 0; nf < 4; ++nf) {
      int c = bn*256 + (nf>>1)*128 + wn*32 + (nf&1)*16 + lr;
#pragma unroll
      for (int rg = 0; rg < 4; ++rg)
        C[(size_t)(r0 + rg) * ldc + c] = (f16)acc[mf][nf][rg];
    }
  }
#undef STAGE_A
#undef STAGE_B
}

// ---------------- GEMM: C[M][N] = A[M][K] * Bw[N][K]^T  (+bias, f32 out) ----------------

template<int OUTF16>
__global__ __launch_bounds__(256) void gemm_bt(
    const f16* __restrict__ A, int lda,
    const f16* __restrict__ Bw,                 // [N][K], ldb = K
    void* __restrict__ Cp, int ldc,
    const float* __restrict__ bias,
    int N, int K) {
  __shared__ alignas(16) f16 As[128 * 32];
  __shared__ alignas(16) f16 Bs[128 * 32];
  int tid = threadIdx.x;
  int w = tid >> 6, l = tid & 63;
  int wm = w >> 1, wn = w & 1;
  int bm = blockIdx.y, bn = blockIdx.x;
  int lr = l & 15, lg = l >> 4;

  f32x4 acc[4][4] = {};

  const int srow = w * 32 + (l >> 2);
  const int scol = (l & 3) * 8;
  const f16* Ab = A  + (size_t)(bm*128 + srow) * lda + scol;
  const f16* Bb = Bw + (size_t)(bn*128 + srow) * K   + scol;
  f16* AsW = &As[w * 1024];
  f16* BsW = &Bs[w * 1024];

  for (int k0 = 0; k0 < K; k0 += 32) {
    gload_lds16(Ab + k0,                     AsW);
    gload_lds16(Ab + k0 + (size_t)16 * lda,  AsW + 512);
    gload_lds16(Bb + k0,                     BsW);
    gload_lds16(Bb + k0 + (size_t)16 * K,    BsW + 512);
    __syncthreads();
    f16x8 af[4], bf[4];
#pragma unroll
    for (int f = 0; f < 4; ++f) {
      af[f] = *(const f16x8*)&As[(wm*64 + f*16 + lr) * 32 + lg * 8];
      bf[f] = *(const f16x8*)&Bs[(wn*64 + f*16 + lr) * 32 + lg * 8];
    }
    __builtin_amdgcn_s_setprio(1);
#pragma unroll
    for (int fr = 0; fr < 4; ++fr)
#pragma unroll
      for (int fc = 0; fc < 4; ++fc)
        acc[fr][fc] = __builtin_amdgcn_mfma_f32_16x16x32_f16(af[fr], bf[fc], acc[fr][fc], 0, 0, 0);
    __builtin_amdgcn_s_setprio(0);
    __syncthreads();
  }

#pragma unroll
  for (int fr = 0; fr < 4; ++fr) {
    int r0 = bm*128 + wm*64 + fr*16 + lg*4;
#pragma unroll
    for (int fc = 0; fc < 4; ++fc) {
      int c = bn*128 + wn*64 + fc*16 + lr;
#pragma unroll
      for (int rg = 0; rg < 4; ++rg) {
        size_t off = (size_t)(r0 + rg) * ldc + c;
        if (OUTF16) ((f16*)Cp)[off] = (f16)acc[fr][fc][rg];
        else        ((float*)Cp)[off] = acc[fr][fc][rg] + bias[c];
      }
    }
  }
}

// ---------------- flash attention v3 ----------------
// grid: (16 q-tiles of 128 rows, 32 bh); 256 thr (4 waves); each wave owns 32
// q-rows as TWO q-groups of 16. Every K/V fragment read from LDS feeds 2 MFMAs
// (one per q-group) -> MFMA:LDS-read ratio 2:1 (was 1:1).
// Swapped QK^T: S^T[kr][q] via mfma(K, Q); PV as O^T = V^T * P^T.
// K staged via global_load_lds into padded [64][168]; V into linear [160][64]
// with XOR-swizzled content (pre-swizzled global source).
__global__ __launch_bounds__(256, 2) void attn(const f16* __restrict__ qkv,
                                               const f16* __restrict__ Vt,
                                               f16* __restrict__ ctx) {
  __shared__ alignas(16) f16 Kl[64 * 168];    // 21504 B
  __shared__ alignas(16) f16 Vl[160 * 64];    // 20480 B
  __shared__ alignas(16) f16 Pl[128 * 72];    // 18432 B   (60416 total, 2 blk/CU)
  int tid = threadIdx.x;
  int wv = tid >> 6, l = tid & 63;
  int lr = l & 15, lg = l >> 4;
  int qt = blockIdx.x, bh = blockIdx.y;
  int b = bh >> 3, h = bh & 7;
  size_t qrow[2];
#pragma unroll
  for (int qg = 0; qg < 2; ++qg)
    qrow[qg] = (size_t)(b*SEQ + qt*128 + wv*32 + qg*16 + lr);

  // Q fragments, pre-scaled by hd^-0.5 * log2(e) (exp2 domain)
  const f16 qscale = (f16)0.114055069f;
  f16x8 qf[2][5];
#pragma unroll
  for (int qg = 0; qg < 2; ++qg)
#pragma unroll
    for (int dk = 0; dk < 5; ++dk) {
      f16x8 t = *(const f16x8*)&qkv[qrow[qg] * NQKV + h*HDIM + dk*32 + lg*8];
#pragma unroll
      for (int j = 0; j < 8; ++j) t[j] = t[j] * qscale;
      qf[qg][dk] = t;
    }

  // K staging: 1344 chunks (5x256 + 64 on wave 0); slot 20 = pad (garbage ok).
  const char* Kg0 = (const char*)qkv + (size_t)(b*SEQ)*NQKV*2 + (size_t)D_MODEL*2 + (size_t)h*HDIM*2;
  char* KlB = (char*)Kl;
  uint32_t koff[6];
  f16* kld[6];
#pragma unroll
  for (int it = 0; it < 6; ++it) {
    int p = (it < 5) ? it*256 + tid : 1280 + (tid & 63);
    koff[it] = (uint32_t)(p/21) * (NQKV*2) + (uint32_t)(p%21) * 16;
    kld[it] = (f16*)(KlB + ((it < 5) ? (it*256 + wv*64)*16 : 1280*16));
  }

  // V staging: 1280 chunks; content XOR-swizzled (phys slot sp holds logical sp^(row&7)).
  const char* Vg0 = (const char*)Vt + (size_t)bh*HDIM*SEQ*2;
  char* VlB = (char*)Vl;
  uint32_t voff[5];
  f16* vld[5];
#pragma unroll
  for (int it = 0; it < 5; ++it) {
    int c = it*256 + tid;
    int row = c >> 3, sp = c & 7;
    voff[it] = (uint32_t)row * (SEQ*2) + (uint32_t)((sp ^ (row & 7)) * 16);
    vld[it] = (f16*)(VlB + (it*256 + wv*64)*16);
  }
  uint32_t vro[2];
#pragma unroll
  for (int ks = 0; ks < 2; ++ks)
    vro[ks] = (uint32_t)lr*128 + (uint32_t)((((ks*4+lg) ^ (lr & 7)) * 16));

  f32x4 oacc[10][2] = {};
  float m[2] = {-1e30f, -1e30f}, lsum[2] = {0.f, 0.f};

  for (int kt = 0; kt < 32; ++kt) {
    const char* Ksrc = Kg0 + (size_t)kt * (64*NQKV*2);
    const char* Vsrc = Vg0 + (size_t)kt * 128;
#pragma unroll
    for (int it = 0; it < 5; ++it) {
      gload_lds16((const f16*)(Ksrc + koff[it]), kld[it]);
      gload_lds16((const f16*)(Vsrc + voff[it]), vld[it]);
    }
    if (wv == 0)
      gload_lds16((const f16*)(Ksrc + koff[5]), kld[5]);
    __syncthreads();

    // S^T[kr][q], both q-groups share each K fragment
    f32x4 sc[4][2] = {};
    __builtin_amdgcn_s_setprio(1);
#pragma unroll
    for (int kb = 0; kb < 4; ++kb)
#pragma unroll
      for (int dk = 0; dk < 5; ++dk) {
        f16x8 a = *(const f16x8*)&Kl[(kb*16 + lr)*168 + dk*32 + lg*8];
        sc[kb][0] = __builtin_amdgcn_mfma_f32_16x16x32_f16(a, qf[0][dk], sc[kb][0], 0, 0, 0);
        sc[kb][1] = __builtin_amdgcn_mfma_f32_16x16x32_f16(a, qf[1][dk], sc[kb][1], 0, 0, 0);
      }
    __builtin_amdgcn_s_setprio(0);

    // online softmax (exp2 domain), lane owns q-rows qrow[0], qrow[1]
    float ps[2][16];
    float smax[2] = {-1e30f, -1e30f};
#pragma unroll
    for (int qg = 0; qg < 2; ++qg)
#pragma unroll
      for (int kb = 0; kb < 4; ++kb)
#pragma unroll
        for (int rg = 0; rg < 4; ++rg) {
          float s = sc[kb][qg][rg];
          ps[qg][kb*4 + rg] = s;
          smax[qg] = fmaxf(smax[qg], s);
        }
#pragma unroll
    for (int qg = 0; qg < 2; ++qg) {
      smax[qg] = fmaxf(smax[qg], __shfl_xor(smax[qg], 16));
      smax[qg] = fmaxf(smax[qg], __shfl_xor(smax[qg], 32));
    }
    if (!__all(fmaxf(smax[0] - m[0], smax[1] - m[1]) <= 11.54f)) {
#pragma unroll
      for (int qg = 0; qg < 2; ++qg) {
        float mn = fmaxf(m[qg], smax[qg]);
        float alpha = exp2f(m[qg] - mn);
#pragma unroll
        for (int df = 0; df < 10; ++df)
#pragma unroll
          for (int rg = 0; rg < 4; ++rg) oacc[df][qg][rg] *= alpha;
        lsum[qg] *= alpha;
        m[qg] = mn;
      }
    }
#pragma unroll
    for (int qg = 0; qg < 2; ++qg) {
      float psum = 0.f;
#pragma unroll
      for (int i = 0; i < 16; ++i) { float p = exp2f(ps[qg][i] - m[qg]); ps[qg][i] = p; psum += p; }
      psum += __shfl_xor(psum, 16);
      psum += __shfl_xor(psum, 32);
      lsum[qg] += psum;
    }

    // P (f16) -> wave-private LDS rows
#pragma unroll
    for (int qg = 0; qg < 2; ++qg)
#pragma unroll
      for (int kb = 0; kb < 4; ++kb) {
        f16x4 pv = { (f16)ps[qg][kb*4+0], (f16)ps[qg][kb*4+1], (f16)ps[qg][kb*4+2], (f16)ps[qg][kb*4+3] };
        *(f16x4*)&Pl[(wv*32 + qg*16 + lr)*72 + kb*16 + lg*4] = pv;
      }
    f16x8 pb[2][2];
#pragma unroll
    for (int qg = 0; qg < 2; ++qg)
#pragma unroll
      for (int ks = 0; ks < 2; ++ks)
        pb[qg][ks] = *(const f16x8*)&Pl[(wv*32 + qg*16 + lr)*72 + ks*32 + lg*8];

    // PV: each V fragment feeds both q-groups
    __builtin_amdgcn_s_setprio(1);
#pragma unroll
    for (int df = 0; df < 10; ++df)
#pragma unroll
      for (int ks = 0; ks < 2; ++ks) {
        f16x8 a = *(const f16x8*)(VlB + vro[ks] + df*2048);
        oacc[df][0] = __builtin_amdgcn_mfma_f32_16x16x32_f16(a, pb[0][ks], oacc[df][0], 0, 0, 0);
        oacc[df][1] = __builtin_amdgcn_mfma_f32_16x16x32_f16(a, pb[1][ks], oacc[df][1], 0, 0, 0);
      }
    __builtin_amdgcn_s_setprio(0);
    __syncthreads();
  }

#pragma unroll
  for (int qg = 0; qg < 2; ++qg) {
    float inv = 1.f / lsum[qg];
#pragma unroll
    for (int df = 0; df < 10; ++df)
#pragma unroll
      for (int pr = 0; pr < 2; ++pr) {
        f16x2 pv = { (f16)(oacc[df][qg][pr*2+0] * inv), (f16)(oacc[df][qg][pr*2+1] * inv) };
        *(f16x2*)&ctx[qrow[qg] * D_MODEL + h*HDIM + df*16 + lg*4 + pr*2] = pv;
      }
  }
}

// ---------------- launcher ----------------

extern "C" void kernel_launch(void* const* d_in, const int* in_sizes, int n_in,
                              void* d_out, int out_size, void* d_ws, size_t ws_size,
                              hipStream_t stream) {
  const float* x   = (const float*)d_in[0];
  const float* Wq  = (const float*)d_in[1];
  const float* Wk  = (const float*)d_in[2];
  const float* Wv  = (const float*)d_in[3];
  const float* Wo  = (const float*)d_in[4];
  const float* bo  = (const float*)d_in[5];
  const float* q_down = (const float*)d_in[6];
  const float* q_up   = (const float*)d_in[7];
  const float* k_down = (const float*)d_in[8];
  const float* k_up   = (const float*)d_in[9];
  const float* v_down = (const float*)d_in[10];
  const float* v_up   = (const float*)d_in[11];
  const float* o_down = (const float*)d_in[12];
  const float* o_up   = (const float*)d_in[13];
  float* out = (float*)d_out;

  char* ws = (char*)d_ws;
  f16* xh    = (f16*)ws;                                  // 8192x1280 (reused as ctx)
  f16* Wqkv  = (f16*)(ws + 20971520);                     // 3840x1280
  f16* WoE   = (f16*)(ws + 20971520 + 9830400);           // 1280x1280
  f16* qkv   = (f16*)(ws + 20971520 + 9830400 + 3276800); // 8192x3840
  f16* Vt    = (f16*)(ws + 20971520 + 9830400 + 3276800 + 62914560); // 32x160x2048
  f16* ctx   = xh;

  convert_f32_to_f16<<<(MTOT*D_MODEL/4 + 255)/256, 256, 0, stream>>>(x, xh, MTOT*D_MODEL/4);
  build_weff<<<D_MODEL*D_MODEL/4/256, 256, 0, stream>>>(Wq, q_up, q_down, Wqkv);
  build_weff<<<D_MODEL*D_MODEL/4/256, 256, 0, stream>>>(Wk, k_up, k_down, Wqkv + (size_t)D_MODEL*D_MODEL);
  build_weff<<<D_MODEL*D_MODEL/4/256, 256, 0, stream>>>(Wv, v_up, v_down, Wqkv + (size_t)2*D_MODEL*D_MODEL);
  build_weff<<<D_MODEL*D_MODEL/4/256, 256, 0, stream>>>(Wo, o_up, o_down, WoE);

  gemm256<<<dim3(NQKV/256, MTOT/256), 512, 0, stream>>>(xh, Wqkv, qkv);
  transpose_v<<<dim3(SEQ/32, HDIM/32, BATCH*HEADS), 256, 0, stream>>>(qkv, Vt);
  attn<<<dim3(SEQ/128, BATCH*HEADS), 256, 0, stream>>>(qkv, Vt, ctx);
  gemm_bt<0><<<dim3(D_MODEL/128, MTOT/128), 256, 0, stream>>>(ctx, D_MODEL, WoE, out, D_MODEL,
                                                              bo, D_MODEL, D_MODEL);
  (void)in_sizes; (void)n_in; (void)out_size; (void)ws_size;
}